// Round 8
// baseline (114.930 us; speedup 1.0000x reference)
//
#include <hip/hip_runtime.h>
#include <hip/hip_fp16.h>
#include <math.h>

#define PATCH 41
#define PSIZE (PATCH * PATCH)   // 1681
#define NUM_ANG 8
#define KS 16
#define STRIDE 10
#define PAD 4
#define DESC 128
#define CLIPVAL 0.2f

__device__ __forceinline__ float block_sum256(float v, float* red, int tid) {
    #pragma unroll
    for (int off = 32; off >= 1; off >>= 1) v += __shfl_xor(v, off);
    __syncthreads();
    if ((tid & 63) == 0) red[tid >> 6] = v;
    __syncthreads();
    return red[0] + red[1] + red[2] + red[3];
}

// gradient -> orientation r in octant units [0,8], |err|<=~1.3e-5
__device__ __forceinline__ float2 grad_om(float gx, float gy, float gkv) {
    const float mag = sqrtf(gx * gx + gy * gy + 1e-10f) * gkv * 1024.0f;
    const float gxp = gx + 1e-10f;
    const float ax = fabsf(gxp), ay = fabsf(gy);
    const float mx = fmaxf(fmaxf(ax, ay), 1e-20f);
    const float t  = fminf(ax, ay) / mx;
    const float s  = t * t;
    float r = t * (1.27306897f + s * (-0.42055650f + s * (0.22936229f
                  + s * (-0.10839420f + s * 0.02652810f))));
    if (ay > ax)     r = 2.0f - r;
    if (gxp < 0.0f)  r = 4.0f - r;
    if (gy < 0.0f)   r = 8.0f - r;          // in [0, 8]
    return make_float2(r, mag);
}

// ---------------- kernel A: streaming per-pixel (o, m) -> packed u32 ----------------
// No LDS, no barriers. 4 consecutive flat pixels per thread, aligned uint4 store.
__global__ __launch_bounds__(256) void om_kernel(
    const float* __restrict__ input,
    const float* __restrict__ gk,
    unsigned int* __restrict__ om)
{
    const int g0 = (blockIdx.x * 256 + threadIdx.x) * 4;   // flat pixel base
    unsigned int pk4[4];

    #pragma unroll
    for (int k = 0; k < 4; ++k) {
        const int pf = g0 + k;
        const int b  = pf / PSIZE;               // magic-mul div
        const int p  = pf - b * PSIZE;
        const int y  = p / PATCH;
        const int x  = p - y * PATCH;
        const float* in_p = input + (size_t)b * PSIZE;

        const int xm = max(x - 1, 0), xp = min(x + 1, PATCH - 1);
        const int ym = max(y - 1, 0), yp = min(y + 1, PATCH - 1);

        const float gx = 0.5f * (in_p[y * PATCH + xp] - in_p[y * PATCH + xm]);
        const float gy = 0.5f * (in_p[yp * PATCH + x] - in_p[ym * PATCH + x]);

        const float2 omv = grad_om(gx, gy, gk[p]);
        const unsigned int ofix = (unsigned int)(int)rintf(omv.x * 4096.0f); // <= 32768
        const unsigned int mbit = (unsigned int)__half_as_ushort(__float2half(omv.y));
        pk4[k] = ofix | (mbit << 16);
    }
    *(uint4*)(om + g0) = make_uint4(pk4[0], pk4[1], pk4[2], pk4[3]);
}

// ---------------- kernel B: scatter + pooling + norm (R4 structure) ----------------
__global__ __launch_bounds__(256) void pool_kernel(
    const unsigned int* __restrict__ om,
    float* __restrict__ out)
{
    __shared__ __half s_arr[PSIZE * NUM_ANG];   // 26896 B, [p][a] interleaved
    __shared__ float  s_cs[PATCH * 32];         // 5248 B
    __shared__ float  s_red[4];

    const int tid = threadIdx.x;
    const int b   = blockIdx.x;

    // exact separable pooling weights: w1r[d] = (d<8 ? d+0.5 : 15.5-d)/8
    const float w1r[KS] = {0.0625f, 0.1875f, 0.3125f, 0.4375f,
                           0.5625f, 0.6875f, 0.8125f, 0.9375f,
                           0.9375f, 0.8125f, 0.6875f, 0.5625f,
                           0.4375f, 0.3125f, 0.1875f, 0.0625f};

    // zero the angle array
    {
        float4* z = (float4*)s_arr;             // 1681 x 16B
        const float4 zero = make_float4(0.f, 0.f, 0.f, 0.f);
        for (int i = tid; i < PSIZE; i += 256) z[i] = zero;
    }
    __syncthreads();

    // scatter: unpack (o, m) -> two f16 slot writes (exclusive per pixel)
    for (int p = tid; p < PSIZE; p += 256) {
        const unsigned int v = om[(size_t)b * PSIZE + p];
        const float o = (float)(v & 0xFFFFu) * (1.0f / 4096.0f);
        const float m = __half2float(__ushort_as_half((unsigned short)(v >> 16)));
        const float bo0f = floorf(o);
        const float f    = o - bo0f;
        const int bo0 = ((int)bo0f) & (NUM_ANG - 1);
        const int bo1 = (bo0 + 1) & (NUM_ANG - 1);
        __half* slot = s_arr + p * NUM_ANG;
        slot[bo0] = __float2half((1.0f - f) * m);
        slot[bo1] = __float2half(f * m);
    }
    __syncthreads();

    // x-pooling: thread = (angle-pair, j-window, y-slice)
    {
        const int a0 = (tid & 3) * 2;
        const int j  = (tid >> 2) & 3;
        const int y0 = tid >> 4;               // 0..15
        const int px0 = j * STRIDE - PAD;
        for (int y = y0; y < PATCH; y += 16) {
            float acc0 = 0.0f, acc1 = 0.0f;
            const int rowbase = y * PATCH;
            #pragma unroll
            for (int dx = 0; dx < KS; ++dx) {
                const int px  = px0 + dx;
                const int pxc = min(max(px, 0), PATCH - 1);
                const float wv = (px == pxc) ? w1r[dx] : 0.0f;
                const __half2 h = *(const __half2*)(s_arr + (rowbase + pxc) * NUM_ANG + a0);
                acc0 = fmaf(wv, __half2float(h.x), acc0);
                acc1 = fmaf(wv, __half2float(h.y), acc1);
            }
            *(float2*)(s_cs + y * 32 + j * 8 + a0) = make_float2(acc0, acc1);
        }
    }
    __syncthreads();

    // y-pooling -> one descriptor value per tid < 128
    float v = 0.0f;
    int a = 0, jj = 0, ii = 0;
    if (tid < DESC) {
        a = tid & 7; jj = (tid >> 3) & 3; ii = tid >> 5;
        const int py0 = ii * STRIDE - PAD;
        #pragma unroll
        for (int dy = 0; dy < KS; ++dy) {
            const int py  = py0 + dy;
            const int pyc = min(max(py, 0), PATCH - 1);
            const float wv = (py == pyc) ? w1r[dy] : 0.0f;
            v = fmaf(wv, s_cs[pyc * 32 + jj * 8 + a], v);
        }
    }

    // normalization chain: l2n -> clip -> l2n -> rootsift
    const float ss1 = block_sum256(v * v, s_red, tid);
    float aa = v / fmaxf(sqrtf(ss1), 1e-12f);
    aa = fminf(fmaxf(aa, 0.0f), CLIPVAL);

    const float ss2 = block_sum256(aa * aa, s_red, tid);
    const float bn = aa / fmaxf(sqrtf(ss2), 1e-12f);

    const float l1 = block_sum256(fabsf(bn), s_red, tid);
    const float o  = sqrtf(bn / fmaxf(l1, 1e-12f) + 1e-10f);

    if (tid < DESC) out[(size_t)b * DESC + (a * 16 + ii * 4 + jj)] = o;
}

// ---------------- fallback: fused single kernel (proven round-4 path) ----------------
__global__ __launch_bounds__(256) void fused_kernel(
    const float* __restrict__ input,
    const float* __restrict__ gk,
    float* __restrict__ out)
{
    __shared__ __half s_arr[PSIZE * NUM_ANG];
    __shared__ float  s_patch[PSIZE];
    __shared__ float  s_cs[PATCH * 32];
    __shared__ float  s_red[4];

    const int tid = threadIdx.x;
    const int b   = blockIdx.x;
    const float* in_p = input + (size_t)b * PSIZE;

    const float w1r[KS] = {0.0625f, 0.1875f, 0.3125f, 0.4375f,
                           0.5625f, 0.6875f, 0.8125f, 0.9375f,
                           0.9375f, 0.8125f, 0.6875f, 0.5625f,
                           0.4375f, 0.3125f, 0.1875f, 0.0625f};

    for (int p = tid; p < PSIZE; p += 256) s_patch[p] = in_p[p];
    {
        float4* z = (float4*)s_arr;
        const float4 zero = make_float4(0.f, 0.f, 0.f, 0.f);
        for (int i = tid; i < PSIZE; i += 256) z[i] = zero;
    }
    __syncthreads();

    for (int p = tid; p < PSIZE; p += 256) {
        const int y = p / PATCH;
        const int x = p - y * PATCH;
        const int xm = max(x - 1, 0), xp = min(x + 1, PATCH - 1);
        const int ym = max(y - 1, 0), yp = min(y + 1, PATCH - 1);
        const float gx = 0.5f * (s_patch[y * PATCH + xp] - s_patch[y * PATCH + xm]);
        const float gy = 0.5f * (s_patch[yp * PATCH + x] - s_patch[ym * PATCH + x]);
        const float2 omv = grad_om(gx, gy, gk[p]);
        const float bo0f = floorf(omv.x);
        const float f    = omv.x - bo0f;
        const int bo0 = ((int)bo0f) & (NUM_ANG - 1);
        const int bo1 = (bo0 + 1) & (NUM_ANG - 1);
        __half* slot = s_arr + p * NUM_ANG;
        slot[bo0] = __float2half((1.0f - f) * omv.y);
        slot[bo1] = __float2half(f * omv.y);
    }
    __syncthreads();

    {
        const int a0 = (tid & 3) * 2;
        const int j  = (tid >> 2) & 3;
        const int y0 = tid >> 4;
        const int px0 = j * STRIDE - PAD;
        for (int y = y0; y < PATCH; y += 16) {
            float acc0 = 0.0f, acc1 = 0.0f;
            const int rowbase = y * PATCH;
            #pragma unroll
            for (int dx = 0; dx < KS; ++dx) {
                const int px  = px0 + dx;
                const int pxc = min(max(px, 0), PATCH - 1);
                const float wv = (px == pxc) ? w1r[dx] : 0.0f;
                const __half2 h = *(const __half2*)(s_arr + (rowbase + pxc) * NUM_ANG + a0);
                acc0 = fmaf(wv, __half2float(h.x), acc0);
                acc1 = fmaf(wv, __half2float(h.y), acc1);
            }
            *(float2*)(s_cs + y * 32 + j * 8 + a0) = make_float2(acc0, acc1);
        }
    }
    __syncthreads();

    float v = 0.0f;
    int a = 0, jj = 0, ii = 0;
    if (tid < DESC) {
        a = tid & 7; jj = (tid >> 3) & 3; ii = tid >> 5;
        const int py0 = ii * STRIDE - PAD;
        #pragma unroll
        for (int dy = 0; dy < KS; ++dy) {
            const int py  = py0 + dy;
            const int pyc = min(max(py, 0), PATCH - 1);
            const float wv = (py == pyc) ? w1r[dy] : 0.0f;
            v = fmaf(wv, s_cs[pyc * 32 + jj * 8 + a], v);
        }
    }

    const float ss1 = block_sum256(v * v, s_red, tid);
    float aa = v / fmaxf(sqrtf(ss1), 1e-12f);
    aa = fminf(fmaxf(aa, 0.0f), CLIPVAL);
    const float ss2 = block_sum256(aa * aa, s_red, tid);
    const float bn = aa / fmaxf(sqrtf(ss2), 1e-12f);
    const float l1 = block_sum256(fabsf(bn), s_red, tid);
    const float o  = sqrtf(bn / fmaxf(l1, 1e-12f) + 1e-10f);

    if (tid < DESC) out[(size_t)b * DESC + (a * 16 + ii * 4 + jj)] = o;
}

extern "C" void kernel_launch(void* const* d_in, const int* in_sizes, int n_in,
                              void* d_out, int out_size, void* d_ws, size_t ws_size,
                              hipStream_t stream) {
    const float* input = (const float*)d_in[0];
    const float* gk    = (const float*)d_in[1];
    float* out         = (float*)d_out;

    const int B = in_sizes[0] / PSIZE;
    if (B <= 0) return;

    const size_t need = (size_t)B * PSIZE * sizeof(unsigned int);
    const long long total_px = (long long)B * PSIZE;

    if (ws_size >= need && (total_px % 1024) == 0) {
        unsigned int* om = (unsigned int*)d_ws;
        const int gridA = (int)(total_px / 1024);      // 4 px/thread, 256 threads
        om_kernel<<<dim3(gridA), dim3(256), 0, stream>>>(input, gk, om);
        pool_kernel<<<dim3(B), dim3(256), 0, stream>>>(om, out);
    } else {
        fused_kernel<<<dim3(B), dim3(256), 0, stream>>>(input, gk, out);
    }
}

// Round 9
// 57.562 us; speedup vs baseline: 1.9966x; 1.9966x over previous
//
#include <hip/hip_runtime.h>
#include <hip/hip_fp16.h>
#include <math.h>

#define PATCH 41
#define PSIZE (PATCH * PATCH)   // 1681
#define NUM_ANG 8
#define KS 16
#define STRIDE 10
#define PAD 4
#define DESC 128
#define CLIPVAL 0.2f
#define ROWQ 11
#define NQUAD (PATCH * ROWQ)    // 451

struct F4 { float x, y, z, w; };   // natural align 4 -> unaligned-capable dwordx4

__device__ __forceinline__ float block_sum256(float v, float* red, int tid) {
    #pragma unroll
    for (int off = 32; off >= 1; off >>= 1) v += __shfl_xor(v, off);
    __syncthreads();
    if ((tid & 63) == 0) red[tid >> 6] = v;
    __syncthreads();
    return red[0] + red[1] + red[2] + red[3];
}

// per-pixel: gradient -> orientation hat weights -> two f16 slot writes
__device__ __forceinline__ void bin_px(__half* slot, float gx, float gy, float gkv) {
    float g2 = fmaf(gx, gx, 1e-10f);
    g2 = fmaf(gy, gy, g2);
    const float mag = __builtin_amdgcn_sqrtf(g2) * (gkv * 1024.0f);

    const float gxp = gx + 1e-10f;
    const float ax = fabsf(gxp), ay = fabsf(gy);
    const float mx = fmaxf(ax, ay);
    const float mn = fminf(ax, ay);
    const float t  = mn * __builtin_amdgcn_rcpf(fmaxf(mx, 1e-20f));
    const float s  = t * t;
    float r = t * fmaf(s, fmaf(s, fmaf(s, fmaf(s, 0.02652810f, -0.10839420f),
                                       0.22936229f), -0.42055650f), 1.27306897f);
    r = (ay > ax)    ? 2.0f - r : r;
    r = (gxp < 0.0f) ? 4.0f - r : r;
    r = (gy < 0.0f)  ? 8.0f - r : r;      // octant units in [0, 8]

    const float bf = floorf(r);
    const float f  = r - bf;
    const int b0 = ((int)bf) & (NUM_ANG - 1);
    const int b1 = (b0 + 1) & (NUM_ANG - 1);
    slot[b0] = __float2half((1.0f - f) * mag);
    slot[b1] = __float2half(f * mag);
}

__global__ __launch_bounds__(256) void sift_desc_kernel(
    const float* __restrict__ input,
    const float* __restrict__ gk,
    float* __restrict__ out)
{
    __shared__ __half s_arr[PSIZE * NUM_ANG];   // [p][a] interleaved, 26896 B
    __shared__ float  s_cs[PATCH * 32];         // 5248 B
    __shared__ float  s_red[4];

    const int tid = threadIdx.x;
    const int b   = blockIdx.x;
    const float* in_p = input + (size_t)b * PSIZE;

    // exact separable pooling weights: w1r[d] = (d<8 ? d+0.5 : 15.5-d)/8
    const float w1r[KS] = {0.0625f, 0.1875f, 0.3125f, 0.4375f,
                           0.5625f, 0.6875f, 0.8125f, 0.9375f,
                           0.9375f, 0.8125f, 0.6875f, 0.5625f,
                           0.4375f, 0.3125f, 0.1875f, 0.0625f};

    // ---- phase 0: zero the angle array ----
    {
        float4* z = (float4*)s_arr;             // 1681 x 16B
        const float4 zero = make_float4(0.f, 0.f, 0.f, 0.f);
        for (int i = tid; i < PSIZE; i += 256) z[i] = zero;
    }
    __syncthreads();

    // ---- phase 1: quad-vector loads from global, gradients in registers ----
    for (int q = tid; q < NQUAD; q += 256) {
        const int y  = q / ROWQ;
        const int xq = (q - y * ROWQ) * 4;
        const int ym = max(y - 1, 0), yp = min(y + 1, PATCH - 1);
        const float* cr = in_p + y  * PATCH;
        const float* ur = in_p + ym * PATCH;
        const float* dr = in_p + yp * PATCH;
        const float* gr = gk + y * PATCH;

        if (xq < 40) {           // 4-pixel quad, x = xq..xq+3 (<= 39)
            const F4 c = *(const F4*)(cr + xq);
            const F4 u = *(const F4*)(ur + xq);
            const F4 d = *(const F4*)(dr + xq);
            const F4 g = *(const F4*)(gr + xq);
            const float L = cr[max(xq - 1, 0)];
            const float R = cr[xq + 4];

            __half* slot = s_arr + (y * PATCH + xq) * NUM_ANG;
            bin_px(slot,      0.5f*(c.y - L),   0.5f*(d.x - u.x), g.x);
            bin_px(slot + 8,  0.5f*(c.z - c.x), 0.5f*(d.y - u.y), g.y);
            bin_px(slot + 16, 0.5f*(c.w - c.y), 0.5f*(d.z - u.z), g.z);
            bin_px(slot + 24, 0.5f*(R  - c.z),  0.5f*(d.w - u.w), g.w);
        } else {                 // ragged tail: single pixel x = 40
            __half* slot = s_arr + (y * PATCH + 40) * NUM_ANG;
            bin_px(slot, 0.5f*(cr[40] - cr[39]), 0.5f*(dr[40] - ur[40]), gr[40]);
        }
    }
    __syncthreads();

    // ---- phase 2a: x-pooling; thread = (angle-pair, j-window, y-slice) ----
    {
        const int a0 = (tid & 3) * 2;
        const int j  = (tid >> 2) & 3;
        const int y0 = tid >> 4;               // 0..15
        const int px0 = j * STRIDE - PAD;
        for (int y = y0; y < PATCH; y += 16) {
            float acc0 = 0.0f, acc1 = 0.0f;
            const int rowbase = y * PATCH;
            #pragma unroll
            for (int dx = 0; dx < KS; ++dx) {
                const int px  = px0 + dx;
                const int pxc = min(max(px, 0), PATCH - 1);
                const float wv = (px == pxc) ? w1r[dx] : 0.0f;
                const __half2 h = *(const __half2*)(s_arr + (rowbase + pxc) * NUM_ANG + a0);
                acc0 = fmaf(wv, __half2float(h.x), acc0);
                acc1 = fmaf(wv, __half2float(h.y), acc1);
            }
            *(float2*)(s_cs + y * 32 + j * 8 + a0) = make_float2(acc0, acc1);
        }
    }
    __syncthreads();

    // ---- phase 2b: y-pooling -> one descriptor value per tid < 128 ----
    float v = 0.0f;
    int a = 0, jj = 0, ii = 0;
    if (tid < DESC) {
        a = tid & 7; jj = (tid >> 3) & 3; ii = tid >> 5;
        const int py0 = ii * STRIDE - PAD;
        #pragma unroll
        for (int dy = 0; dy < KS; ++dy) {
            const int py  = py0 + dy;
            const int pyc = min(max(py, 0), PATCH - 1);
            const float wv = (py == pyc) ? w1r[dy] : 0.0f;
            v = fmaf(wv, s_cs[pyc * 32 + jj * 8 + a], v);
        }
    }

    // ---- normalization chain: l2n -> clip -> l2n -> rootsift ----
    const float ss1 = block_sum256(v * v, s_red, tid);
    float aa = v / fmaxf(sqrtf(ss1), 1e-12f);
    aa = fminf(fmaxf(aa, 0.0f), CLIPVAL);

    const float ss2 = block_sum256(aa * aa, s_red, tid);
    const float bn = aa / fmaxf(sqrtf(ss2), 1e-12f);

    const float l1 = block_sum256(fabsf(bn), s_red, tid);
    const float o  = sqrtf(bn / fmaxf(l1, 1e-12f) + 1e-10f);

    // reference layout: desc[ang*16 + i*4 + j]
    if (tid < DESC) out[(size_t)b * DESC + (a * 16 + ii * 4 + jj)] = o;
}

extern "C" void kernel_launch(void* const* d_in, const int* in_sizes, int n_in,
                              void* d_out, int out_size, void* d_ws, size_t ws_size,
                              hipStream_t stream) {
    const float* input = (const float*)d_in[0];
    const float* gk    = (const float*)d_in[1];
    float* out         = (float*)d_out;

    const int B = in_sizes[0] / PSIZE;
    if (B <= 0) return;
    sift_desc_kernel<<<dim3(B), dim3(256), 0, stream>>>(input, gk, out);
}

// Round 10
// 56.823 us; speedup vs baseline: 2.0226x; 1.0130x over previous
//
#include <hip/hip_runtime.h>
#include <hip/hip_fp16.h>
#include <math.h>

#define PATCH 41
#define PSIZE (PATCH * PATCH)   // 1681
#define NUM_ANG 8
#define KS 16
#define STRIDE 10
#define PAD 4
#define DESC 128
#define CLIPVAL 0.2f
#define ROWQ 11
#define NQUAD (PATCH * ROWQ)    // 451

#define PROW 42                  // plane row stride (halves): 41 + zero pad col
#define PLANE (PATCH * PROW)     // 1722 halves per angle plane
#define CST 32                   // colsum row stride (floats)

struct F4 { float x, y, z, w; };   // natural align 4 -> unaligned-capable dwordx4

#if __has_builtin(__builtin_amdgcn_fdot2)
#define HAVE_FDOT2 1
typedef _Float16 h2v __attribute__((ext_vector_type(2)));
#endif

__device__ __forceinline__ float block_sum256(float v, float* red, int tid) {
    #pragma unroll
    for (int off = 32; off >= 1; off >>= 1) v += __shfl_xor(v, off);
    __syncthreads();
    if ((tid & 63) == 0) red[tid >> 6] = v;
    __syncthreads();
    return red[0] + red[1] + red[2] + red[3];
}

// per-pixel: gradient -> orientation hat weights -> two b16 plane writes
__device__ __forceinline__ void bin_px(__half* harr, int yx, float gx, float gy, float gkv) {
    float g2 = fmaf(gx, gx, 1e-10f);
    g2 = fmaf(gy, gy, g2);
    const float mag = __builtin_amdgcn_sqrtf(g2) * (gkv * 1024.0f);

    const float gxp = gx + 1e-10f;
    const float ax = fabsf(gxp), ay = fabsf(gy);
    const float mx = fmaxf(ax, ay);
    const float mn = fminf(ax, ay);
    const float t  = mn * __builtin_amdgcn_rcpf(fmaxf(mx, 1e-20f));
    const float s  = t * t;
    float r = t * fmaf(s, fmaf(s, fmaf(s, fmaf(s, 0.02652810f, -0.10839420f),
                                       0.22936229f), -0.42055650f), 1.27306897f);
    r = (ay > ax)    ? 2.0f - r : r;
    r = (gxp < 0.0f) ? 4.0f - r : r;
    r = (gy < 0.0f)  ? 8.0f - r : r;      // octant units in [0, 8]

    const float bf = floorf(r);
    const float f  = r - bf;
    const int b0 = ((int)bf) & (NUM_ANG - 1);
    const int b1 = (b0 + 1) & (NUM_ANG - 1);
    harr[b0 * PLANE + yx] = __float2half((1.0f - f) * mag);
    harr[b1 * PLANE + yx] = __float2half(f * mag);
}

__global__ __launch_bounds__(256) void sift_desc_kernel(
    const float* __restrict__ input,
    const float* __restrict__ gk,
    float* __restrict__ out)
{
    __shared__ __half s_arr[NUM_ANG * PLANE];   // 27552 B, planar per-angle
    __shared__ float  s_cs[PATCH * CST];        // 5248 B
    __shared__ float  s_red[4];

    const int tid = threadIdx.x;
    const int b   = blockIdx.x;
    const float* in_p = input + (size_t)b * PSIZE;
    __half* harr = s_arr;

    // exact separable pooling weights for y-pool: w1r[d] = (min(d,15-d)+0.5)/8
    const float w1r[KS] = {0.0625f, 0.1875f, 0.3125f, 0.4375f,
                           0.5625f, 0.6875f, 0.8125f, 0.9375f,
                           0.9375f, 0.8125f, 0.6875f, 0.5625f,
                           0.4375f, 0.3125f, 0.1875f, 0.0625f};

    // ---- phase 0: zero the angle planes (incl. pad columns) ----
    {
        float4* z = (float4*)s_arr;             // 1722 x 16B
        const float4 zero = make_float4(0.f, 0.f, 0.f, 0.f);
        for (int i = tid; i < NUM_ANG * PLANE / 8; i += 256) z[i] = zero;
    }
    __syncthreads();

    // ---- phase 1: quad-vector global loads, gradients in registers ----
    for (int q = tid; q < NQUAD; q += 256) {
        const int y  = q / ROWQ;
        const int xq = (q - y * ROWQ) * 4;
        const int ym = max(y - 1, 0), yp = min(y + 1, PATCH - 1);
        const float* cr = in_p + y  * PATCH;
        const float* ur = in_p + ym * PATCH;
        const float* dr = in_p + yp * PATCH;
        const float* gr = gk + y * PATCH;
        const int yx = y * PROW + xq;

        if (xq < 40) {           // 4-pixel quad
            const F4 c = *(const F4*)(cr + xq);
            const F4 u = *(const F4*)(ur + xq);
            const F4 d = *(const F4*)(dr + xq);
            const F4 g = *(const F4*)(gr + xq);
            const float L = cr[max(xq - 1, 0)];
            const float R = cr[xq + 4];

            bin_px(harr, yx,     0.5f*(c.y - L),   0.5f*(d.x - u.x), g.x);
            bin_px(harr, yx + 1, 0.5f*(c.z - c.x), 0.5f*(d.y - u.y), g.y);
            bin_px(harr, yx + 2, 0.5f*(c.w - c.y), 0.5f*(d.z - u.z), g.z);
            bin_px(harr, yx + 3, 0.5f*(R  - c.z),  0.5f*(d.w - u.w), g.w);
        } else {                 // ragged tail: single pixel x = 40
            bin_px(harr, yx, 0.5f*(cr[40] - cr[39]), 0.5f*(dr[40] - ur[40]), gr[40]);
        }
    }
    __syncthreads();

    // ---- phase 2a: x-pooling as 8 half2 dot-pairs; thread = (angle, j, y-slice) ----
    {
        const int a  = tid & 7;
        const int j  = (tid >> 3) & 3;
        const int y0 = tid >> 5;               // 0..7
        const int px0  = j * STRIDE - PAD;     // -4, 6, 16, 26 (all even)
        const int px0c = max(px0, 0);

        // weight pairs: w(d) = max(0, 1 - |d - 7.5|/8), d = px - px0
#ifdef HAVE_FDOT2
        h2v wp[8];
#else
        float wpf[16];
#endif
        #pragma unroll
        for (int t = 0; t < 8; ++t) {
            const float d0 = (float)(px0c + 2 * t - px0);
            const float w0 = fmaxf(0.0f, 1.0f - fabsf(d0 - 7.5f) * 0.125f);
            const float w1 = fmaxf(0.0f, 1.0f - fabsf(d0 - 6.5f) * 0.125f);
#ifdef HAVE_FDOT2
            wp[t].x = (_Float16)w0;
            wp[t].y = (_Float16)w1;
#else
            wpf[2 * t]     = w0;
            wpf[2 * t + 1] = w1;
#endif
        }

        const __half* plane = harr + a * PLANE;
        for (int y = y0; y < PATCH; y += 8) {
            const __half* rp = plane + y * PROW + px0c;
            float acc = 0.0f;
            #pragma unroll
            for (int t = 0; t < 8; ++t) {
#ifdef HAVE_FDOT2
                const h2v dv = *(const h2v*)(rp + 2 * t);
                acc = __builtin_amdgcn_fdot2(dv, wp[t], acc, false);
#else
                const __half2 h = *(const __half2*)(rp + 2 * t);
                acc = fmaf(wpf[2 * t],     __half2float(h.x), acc);
                acc = fmaf(wpf[2 * t + 1], __half2float(h.y), acc);
#endif
            }
            s_cs[y * CST + j * 8 + a] = acc;
        }
    }
    __syncthreads();

    // ---- phase 2b: y-pooling -> one descriptor value per tid < 128 ----
    float v = 0.0f;
    int a = 0, jj = 0, ii = 0;
    if (tid < DESC) {
        a = tid & 7; jj = (tid >> 3) & 3; ii = tid >> 5;
        const int py0 = ii * STRIDE - PAD;
        #pragma unroll
        for (int dy = 0; dy < KS; ++dy) {
            const int py  = py0 + dy;
            const int pyc = min(max(py, 0), PATCH - 1);
            const float wv = (py == pyc) ? w1r[dy] : 0.0f;
            v = fmaf(wv, s_cs[pyc * CST + jj * 8 + a], v);
        }
    }

    // ---- normalization chain: l2n -> clip -> l2n -> rootsift ----
    const float ss1 = block_sum256(v * v, s_red, tid);
    float aa = v / fmaxf(sqrtf(ss1), 1e-12f);
    aa = fminf(fmaxf(aa, 0.0f), CLIPVAL);

    const float ss2 = block_sum256(aa * aa, s_red, tid);
    const float bn = aa / fmaxf(sqrtf(ss2), 1e-12f);

    const float l1 = block_sum256(fabsf(bn), s_red, tid);
    const float o  = sqrtf(bn / fmaxf(l1, 1e-12f) + 1e-10f);

    // reference layout: desc[ang*16 + i*4 + j]
    if (tid < DESC) out[(size_t)b * DESC + (a * 16 + ii * 4 + jj)] = o;
}

extern "C" void kernel_launch(void* const* d_in, const int* in_sizes, int n_in,
                              void* d_out, int out_size, void* d_ws, size_t ws_size,
                              hipStream_t stream) {
    const float* input = (const float*)d_in[0];
    const float* gk    = (const float*)d_in[1];
    float* out         = (float*)d_out;

    const int B = in_sizes[0] / PSIZE;
    if (B <= 0) return;
    sift_desc_kernel<<<dim3(B), dim3(256), 0, stream>>>(input, gk, out);
}

// Round 11
// 48.762 us; speedup vs baseline: 2.3569x; 1.1653x over previous
//
#include <hip/hip_runtime.h>
#include <hip/hip_fp16.h>
#include <math.h>

#define PATCH 41
#define PSIZE (PATCH * PATCH)   // 1681
#define NUM_ANG 8
#define KS 16
#define STRIDE 10
#define PAD 4
#define DESC 128
#define CLIPVAL 0.2f

#define PROW 48                  // plane row stride in halves (96 B, 16B-aligned)
#define PLANE_H 1992             // plane stride in halves (3984 B -> bank stagger 4)
#define NQ4 (PATCH * 10)         // 410 uniform quads (x = 0..39)
#define CST 32                   // colsum row stride (floats)

struct F4 { float x, y, z, w; };

#if __has_builtin(__builtin_amdgcn_fdot2)
#define HAVE_FDOT2 1
typedef _Float16 h2v __attribute__((ext_vector_type(2)));
#endif

__device__ __forceinline__ float block_sum256(float v, float* red, int tid) {
    #pragma unroll
    for (int off = 32; off >= 1; off >>= 1) v += __shfl_xor(v, off);
    __syncthreads();
    if ((tid & 63) == 0) red[tid >> 6] = v;
    __syncthreads();
    return red[0] + red[1] + red[2] + red[3];
}

// per-pixel: gradient -> orientation -> two b16 plane writes
__device__ __forceinline__ void bin_px(__half* harr, int yx, float gx, float gy, float gkv) {
    float g2 = fmaf(gx, gx, 1e-10f);
    g2 = fmaf(gy, gy, g2);
    const float mag = __builtin_amdgcn_sqrtf(g2) * (gkv * 1024.0f);

    const float gxp = gx + 1e-10f;
    const float ax = fabsf(gxp), ay = fabsf(gy);
    const float mx = fmaxf(ax, ay);
    const float mn = fminf(ax, ay);
    const float t  = mn * __builtin_amdgcn_rcpf(fmaxf(mx, 1e-20f));
    const float s  = t * t;
    float r = t * fmaf(s, fmaf(s, fmaf(s, fmaf(s, 0.02652810f, -0.10839420f),
                                       0.22936229f), -0.42055650f), 1.27306897f);
    r = (ay > ax)    ? 2.0f - r : r;
    r = (gxp < 0.0f) ? 4.0f - r : r;
    r = (gy < 0.0f)  ? 8.0f - r : r;      // octant units in [0, 8]

    const float bf = floorf(r);
    const float f  = r - bf;
    const int b0 = ((int)bf) & (NUM_ANG - 1);
    const int b1 = (b0 + 1) & (NUM_ANG - 1);
    harr[b0 * PLANE_H + yx] = __float2half((1.0f - f) * mag);
    harr[b1 * PLANE_H + yx] = __float2half(f * mag);
}

__global__ __launch_bounds__(256) void sift_desc_kernel(
    const float* __restrict__ input,
    const float* __restrict__ gk,
    float* __restrict__ out)
{
    __shared__ __align__(16) __half s_arr[NUM_ANG * PLANE_H];  // 31872 B
    __shared__ float s_cs[PATCH * CST];                        // 5248 B
    __shared__ float s_red[4];

    const int tid = threadIdx.x;
    const int b   = blockIdx.x;
    const float* in_p = input + (size_t)b * PSIZE;
    __half* harr = s_arr;

    const float w1r[KS] = {0.0625f, 0.1875f, 0.3125f, 0.4375f,
                           0.5625f, 0.6875f, 0.8125f, 0.9375f,
                           0.9375f, 0.8125f, 0.6875f, 0.5625f,
                           0.4375f, 0.3125f, 0.1875f, 0.0625f};

    // ---- phase 0: zero the planes (incl. pad cols + bank-stagger pad) ----
    {
        float4* z = (float4*)s_arr;             // 1992 x 16B
        const float4 zero = make_float4(0.f, 0.f, 0.f, 0.f);
        for (int i = tid; i < NUM_ANG * PLANE_H / 8; i += 256) z[i] = zero;
    }
    __syncthreads();

    // ---- phase 1: uniform quads (x=0..39) + uniform tail pass (x=40) ----
    for (int q = tid; q < NQ4; q += 256) {
        const int y  = q / 10;
        const int xq = (q - y * 10) * 4;
        const int ym = max(y - 1, 0), yp = min(y + 1, PATCH - 1);
        const float* cr = in_p + y  * PATCH;
        const float* ur = in_p + ym * PATCH;
        const float* dr = in_p + yp * PATCH;
        const float* gr = gk + y * PATCH;
        const int yx = y * PROW + xq;

        const F4 c = *(const F4*)(cr + xq);
        const F4 u = *(const F4*)(ur + xq);
        const F4 d = *(const F4*)(dr + xq);
        const F4 g = *(const F4*)(gr + xq);
        const float L = cr[max(xq - 1, 0)];
        const float R = cr[xq + 4];

        bin_px(harr, yx,     0.5f*(c.y - L),   0.5f*(d.x - u.x), g.x);
        bin_px(harr, yx + 1, 0.5f*(c.z - c.x), 0.5f*(d.y - u.y), g.y);
        bin_px(harr, yx + 2, 0.5f*(c.w - c.y), 0.5f*(d.z - u.z), g.z);
        bin_px(harr, yx + 3, 0.5f*(R  - c.z),  0.5f*(d.w - u.w), g.w);
    }
    if (tid < PATCH) {           // tail column x = 40
        const int y = tid;
        const int ym = max(y - 1, 0), yp = min(y + 1, PATCH - 1);
        const float* cr = in_p + y * PATCH;
        bin_px(harr, y * PROW + 40,
               0.5f*(cr[40] - cr[39]),
               0.5f*(in_p[yp * PATCH + 40] - in_p[ym * PATCH + 40]),
               gk[y * PATCH + 40]);
    }
    __syncthreads();

    // ---- phase 2a: one item per (angle, y); read row ONCE as 6 b128 ----
    {
        union RowU { float4 f4[6]; __half2 h2[24]; };

        #pragma unroll
        for (int batch = 0; batch < 2; ++batch) {
            const int item = tid + batch * 256;
            if (batch == 1 && tid >= 72) break;         // 328 items total
            const int a = item & 7;
            const int y = item >> 3;

            RowU row;
            const float4* rp = (const float4*)(harr + a * PLANE_H + y * PROW);
            #pragma unroll
            for (int i = 0; i < 6; ++i) row.f4[i] = rp[i];

            float acc0 = 0.f, acc1 = 0.f, acc2 = 0.f, acc3 = 0.f;
#ifdef HAVE_FDOT2
            #define DOT(ACC, P, W0, W1) \
                ACC = __builtin_amdgcn_fdot2(*(const h2v*)&row.h2[P], \
                        (h2v){(_Float16)(W0), (_Float16)(W1)}, ACC, false)
#else
            #define DOT(ACC, P, W0, W1) \
                ACC = fmaf((W0), __half2float(row.h2[P].x), \
                      fmaf((W1), __half2float(row.h2[P].y), ACC))
#endif
            // j=0: px 0..11, weights w1r[4..15]
            DOT(acc0, 0, 0.5625f, 0.6875f); DOT(acc0, 1, 0.8125f, 0.9375f);
            DOT(acc0, 2, 0.9375f, 0.8125f); DOT(acc0, 3, 0.6875f, 0.5625f);
            DOT(acc0, 4, 0.4375f, 0.3125f); DOT(acc0, 5, 0.1875f, 0.0625f);
            // j=1: px 6..21 -> pairs 3..10
            DOT(acc1, 3, 0.0625f, 0.1875f); DOT(acc1, 4, 0.3125f, 0.4375f);
            DOT(acc1, 5, 0.5625f, 0.6875f); DOT(acc1, 6, 0.8125f, 0.9375f);
            DOT(acc1, 7, 0.9375f, 0.8125f); DOT(acc1, 8, 0.6875f, 0.5625f);
            DOT(acc1, 9, 0.4375f, 0.3125f); DOT(acc1, 10, 0.1875f, 0.0625f);
            // j=2: px 16..31 -> pairs 8..15
            DOT(acc2, 8, 0.0625f, 0.1875f); DOT(acc2, 9, 0.3125f, 0.4375f);
            DOT(acc2, 10, 0.5625f, 0.6875f); DOT(acc2, 11, 0.8125f, 0.9375f);
            DOT(acc2, 12, 0.9375f, 0.8125f); DOT(acc2, 13, 0.6875f, 0.5625f);
            DOT(acc2, 14, 0.4375f, 0.3125f); DOT(acc2, 15, 0.1875f, 0.0625f);
            // j=3: px 26..41 -> pairs 13..20 (px 41 is zero pad)
            DOT(acc3, 13, 0.0625f, 0.1875f); DOT(acc3, 14, 0.3125f, 0.4375f);
            DOT(acc3, 15, 0.5625f, 0.6875f); DOT(acc3, 16, 0.8125f, 0.9375f);
            DOT(acc3, 17, 0.9375f, 0.8125f); DOT(acc3, 18, 0.6875f, 0.5625f);
            DOT(acc3, 19, 0.4375f, 0.3125f); DOT(acc3, 20, 0.1875f, 0.0625f);
            #undef DOT

            float* cs = s_cs + y * CST + a;
            cs[0]  = acc0;
            cs[8]  = acc1;
            cs[16] = acc2;
            cs[24] = acc3;
        }
    }
    __syncthreads();

    // ---- phase 2b: y-pooling -> one descriptor value per tid < 128 ----
    float v = 0.0f;
    int a = 0, jj = 0, ii = 0;
    if (tid < DESC) {
        a = tid & 7; jj = (tid >> 3) & 3; ii = tid >> 5;
        const int py0 = ii * STRIDE - PAD;
        #pragma unroll
        for (int dy = 0; dy < KS; ++dy) {
            const int py  = py0 + dy;
            const int pyc = min(max(py, 0), PATCH - 1);
            const float wv = (py == pyc) ? w1r[dy] : 0.0f;
            v = fmaf(wv, s_cs[pyc * CST + jj * 8 + a], v);
        }
    }

    // ---- normalization chain: l2n -> clip -> l2n -> rootsift ----
    const float ss1 = block_sum256(v * v, s_red, tid);
    float aa = v / fmaxf(sqrtf(ss1), 1e-12f);
    aa = fminf(fmaxf(aa, 0.0f), CLIPVAL);

    const float ss2 = block_sum256(aa * aa, s_red, tid);
    const float bn = aa / fmaxf(sqrtf(ss2), 1e-12f);

    const float l1 = block_sum256(fabsf(bn), s_red, tid);
    const float o  = sqrtf(bn / fmaxf(l1, 1e-12f) + 1e-10f);

    // reference layout: desc[ang*16 + i*4 + j]
    if (tid < DESC) out[(size_t)b * DESC + (a * 16 + ii * 4 + jj)] = o;
}

extern "C" void kernel_launch(void* const* d_in, const int* in_sizes, int n_in,
                              void* d_out, int out_size, void* d_ws, size_t ws_size,
                              hipStream_t stream) {
    const float* input = (const float*)d_in[0];
    const float* gk    = (const float*)d_in[1];
    float* out         = (float*)d_out;

    const int B = in_sizes[0] / PSIZE;
    if (B <= 0) return;
    sift_desc_kernel<<<dim3(B), dim3(256), 0, stream>>>(input, gk, out);
}

// Round 12
// 48.740 us; speedup vs baseline: 2.3580x; 1.0005x over previous
//
#include <hip/hip_runtime.h>
#include <hip/hip_fp16.h>
#include <math.h>

#define PATCH 41
#define PSIZE (PATCH * PATCH)   // 1681
#define NUM_ANG 8
#define KS 16
#define STRIDE 10
#define PAD 4
#define DESC 128
#define CLIPVAL 0.2f

#define PROW 42                  // plane row stride in halves = 21 dwords (ODD)
#define PLANE_H 1722             // plane stride in halves = 861 dwords (ODD)
#define NQ4 (PATCH * 10)         // 410 uniform quads (x = 0..39)
#define CST 36                   // colsum row stride (floats) -> banks 4y+a+8j
#define NROWPAIR 21              // half2 pairs per row

struct F4 { float x, y, z, w; };

#if __has_builtin(__builtin_amdgcn_fdot2)
#define HAVE_FDOT2 1
typedef _Float16 h2v __attribute__((ext_vector_type(2)));
#endif

__device__ __forceinline__ float block_sum256(float v, float* red, int tid) {
    #pragma unroll
    for (int off = 32; off >= 1; off >>= 1) v += __shfl_xor(v, off);
    __syncthreads();
    if ((tid & 63) == 0) red[tid >> 6] = v;
    __syncthreads();
    return red[0] + red[1] + red[2] + red[3];
}

// per-pixel: gradient -> orientation -> two b16 plane writes
__device__ __forceinline__ void bin_px(__half* harr, int yx, float gx, float gy, float gkv) {
    float g2 = fmaf(gx, gx, 1e-10f);
    g2 = fmaf(gy, gy, g2);
    const float mag = __builtin_amdgcn_sqrtf(g2) * (gkv * 1024.0f);

    const float gxp = gx + 1e-10f;
    const float ax = fabsf(gxp), ay = fabsf(gy);
    const float mx = fmaxf(ax, ay);
    const float mn = fminf(ax, ay);
    const float t  = mn * __builtin_amdgcn_rcpf(fmaxf(mx, 1e-20f));
    const float s  = t * t;
    float r = t * fmaf(s, fmaf(s, fmaf(s, fmaf(s, 0.02652810f, -0.10839420f),
                                       0.22936229f), -0.42055650f), 1.27306897f);
    r = (ay > ax)    ? 2.0f - r : r;
    r = (gxp < 0.0f) ? 4.0f - r : r;
    r = (gy < 0.0f)  ? 8.0f - r : r;      // octant units in [0, 8]

    const float bf = floorf(r);
    const float f  = r - bf;
    const int b0 = ((int)bf) & (NUM_ANG - 1);
    const int b1 = (b0 + 1) & (NUM_ANG - 1);
    harr[b0 * PLANE_H + yx] = __float2half((1.0f - f) * mag);
    harr[b1 * PLANE_H + yx] = __float2half(f * mag);
}

__global__ __launch_bounds__(256) void sift_desc_kernel(
    const float* __restrict__ input,
    const float* __restrict__ gk,
    float* __restrict__ out)
{
    __shared__ __align__(16) __half s_arr[NUM_ANG * PLANE_H];  // 27552 B
    __shared__ float s_cs[PATCH * CST];                        // 5904 B
    __shared__ float s_red[4];

    const int tid = threadIdx.x;
    const int b   = blockIdx.x;
    const float* in_p = input + (size_t)b * PSIZE;
    __half* harr = s_arr;

    const float w1r[KS] = {0.0625f, 0.1875f, 0.3125f, 0.4375f,
                           0.5625f, 0.6875f, 0.8125f, 0.9375f,
                           0.9375f, 0.8125f, 0.6875f, 0.5625f,
                           0.4375f, 0.3125f, 0.1875f, 0.0625f};

    // ---- phase 0: zero the planes (whole region, b128) ----
    {
        float4* z = (float4*)s_arr;             // 1722 x 16B
        const float4 zero = make_float4(0.f, 0.f, 0.f, 0.f);
        for (int i = tid; i < NUM_ANG * PLANE_H / 8; i += 256) z[i] = zero;
    }
    __syncthreads();

    // ---- phase 1: uniform quads (x=0..39) + tail column (x=40) ----
    for (int q = tid; q < NQ4; q += 256) {
        const int y  = q / 10;
        const int xq = (q - y * 10) * 4;
        const int ym = max(y - 1, 0), yp = min(y + 1, PATCH - 1);
        const float* cr = in_p + y  * PATCH;
        const float* ur = in_p + ym * PATCH;
        const float* dr = in_p + yp * PATCH;
        const float* gr = gk + y * PATCH;
        const int yx = y * PROW + xq;

        const F4 c = *(const F4*)(cr + xq);
        const F4 u = *(const F4*)(ur + xq);
        const F4 d = *(const F4*)(dr + xq);
        const F4 g = *(const F4*)(gr + xq);
        const float L = cr[max(xq - 1, 0)];
        const float R = cr[xq + 4];

        bin_px(harr, yx,     0.5f*(c.y - L),   0.5f*(d.x - u.x), g.x);
        bin_px(harr, yx + 1, 0.5f*(c.z - c.x), 0.5f*(d.y - u.y), g.y);
        bin_px(harr, yx + 2, 0.5f*(c.w - c.y), 0.5f*(d.z - u.z), g.z);
        bin_px(harr, yx + 3, 0.5f*(R  - c.z),  0.5f*(d.w - u.w), g.w);
    }
    if (tid < PATCH) {           // tail column x = 40
        const int y = tid;
        const int ym = max(y - 1, 0), yp = min(y + 1, PATCH - 1);
        const float* cr = in_p + y * PATCH;
        bin_px(harr, y * PROW + 40,
               0.5f*(cr[40] - cr[39]),
               0.5f*(in_p[yp * PATCH + 40] - in_p[ym * PATCH + 40]),
               gk[y * PATCH + 40]);
    }
    __syncthreads();

    // ---- phase 2a: one item per (angle, y); read row ONCE as 21 b32 ----
    {
        #pragma unroll
        for (int batch = 0; batch < 2; ++batch) {
            const int item = tid + batch * 256;
            if (batch == 1 && tid >= 72) break;         // 328 items total
            const int a = item & 7;
            const int y = item >> 3;

            __half2 row[NROWPAIR];
            const __half2* rp = (const __half2*)(harr + a * PLANE_H + y * PROW);
            #pragma unroll
            for (int i = 0; i < NROWPAIR; ++i) row[i] = rp[i];

            float acc0 = 0.f, acc1 = 0.f, acc2 = 0.f, acc3 = 0.f;
#ifdef HAVE_FDOT2
            #define DOT(ACC, P, W0, W1) \
                ACC = __builtin_amdgcn_fdot2(*(const h2v*)&row[P], \
                        (h2v){(_Float16)(W0), (_Float16)(W1)}, ACC, false)
#else
            #define DOT(ACC, P, W0, W1) \
                ACC = fmaf((W0), __half2float(row[P].x), \
                      fmaf((W1), __half2float(row[P].y), ACC))
#endif
            // j=0: px 0..11 -> pairs 0..5, weights w1r[4..15]
            DOT(acc0, 0, 0.5625f, 0.6875f); DOT(acc0, 1, 0.8125f, 0.9375f);
            DOT(acc0, 2, 0.9375f, 0.8125f); DOT(acc0, 3, 0.6875f, 0.5625f);
            DOT(acc0, 4, 0.4375f, 0.3125f); DOT(acc0, 5, 0.1875f, 0.0625f);
            // j=1: px 6..21 -> pairs 3..10
            DOT(acc1, 3, 0.0625f, 0.1875f); DOT(acc1, 4, 0.3125f, 0.4375f);
            DOT(acc1, 5, 0.5625f, 0.6875f); DOT(acc1, 6, 0.8125f, 0.9375f);
            DOT(acc1, 7, 0.9375f, 0.8125f); DOT(acc1, 8, 0.6875f, 0.5625f);
            DOT(acc1, 9, 0.4375f, 0.3125f); DOT(acc1, 10, 0.1875f, 0.0625f);
            // j=2: px 16..31 -> pairs 8..15
            DOT(acc2, 8, 0.0625f, 0.1875f); DOT(acc2, 9, 0.3125f, 0.4375f);
            DOT(acc2, 10, 0.5625f, 0.6875f); DOT(acc2, 11, 0.8125f, 0.9375f);
            DOT(acc2, 12, 0.9375f, 0.8125f); DOT(acc2, 13, 0.6875f, 0.5625f);
            DOT(acc2, 14, 0.4375f, 0.3125f); DOT(acc2, 15, 0.1875f, 0.0625f);
            // j=3: px 26..41 -> pairs 13..20 (half 41 is zero pad)
            DOT(acc3, 13, 0.0625f, 0.1875f); DOT(acc3, 14, 0.3125f, 0.4375f);
            DOT(acc3, 15, 0.5625f, 0.6875f); DOT(acc3, 16, 0.8125f, 0.9375f);
            DOT(acc3, 17, 0.9375f, 0.8125f); DOT(acc3, 18, 0.6875f, 0.5625f);
            DOT(acc3, 19, 0.4375f, 0.3125f); DOT(acc3, 20, 0.1875f, 0.0625f);
            #undef DOT

            float* cs = s_cs + y * CST + a;
            cs[0]  = acc0;
            cs[8]  = acc1;
            cs[16] = acc2;
            cs[24] = acc3;
        }
    }
    __syncthreads();

    // ---- phase 2b: y-pooling -> one descriptor value per tid < 128 ----
    float v = 0.0f;
    int a = 0, jj = 0, ii = 0;
    if (tid < DESC) {
        a = tid & 7; jj = (tid >> 3) & 3; ii = tid >> 5;
        const int py0 = ii * STRIDE - PAD;
        #pragma unroll
        for (int dy = 0; dy < KS; ++dy) {
            const int py  = py0 + dy;
            const int pyc = min(max(py, 0), PATCH - 1);
            const float wv = (py == pyc) ? w1r[dy] : 0.0f;
            v = fmaf(wv, s_cs[pyc * CST + jj * 8 + a], v);
        }
    }

    // ---- normalization chain: l2n -> clip -> l2n -> rootsift ----
    const float ss1 = block_sum256(v * v, s_red, tid);
    float aa = v / fmaxf(sqrtf(ss1), 1e-12f);
    aa = fminf(fmaxf(aa, 0.0f), CLIPVAL);

    const float ss2 = block_sum256(aa * aa, s_red, tid);
    const float bn = aa / fmaxf(sqrtf(ss2), 1e-12f);

    const float l1 = block_sum256(fabsf(bn), s_red, tid);
    const float o  = sqrtf(bn / fmaxf(l1, 1e-12f) + 1e-10f);

    // reference layout: desc[ang*16 + i*4 + j]
    if (tid < DESC) out[(size_t)b * DESC + (a * 16 + ii * 4 + jj)] = o;
}

extern "C" void kernel_launch(void* const* d_in, const int* in_sizes, int n_in,
                              void* d_out, int out_size, void* d_ws, size_t ws_size,
                              hipStream_t stream) {
    const float* input = (const float*)d_in[0];
    const float* gk    = (const float*)d_in[1];
    float* out         = (float*)d_out;

    const int B = in_sizes[0] / PSIZE;
    if (B <= 0) return;
    sift_desc_kernel<<<dim3(B), dim3(256), 0, stream>>>(input, gk, out);
}

// Round 13
// 47.744 us; speedup vs baseline: 2.4072x; 1.0209x over previous
//
#include <hip/hip_runtime.h>
#include <hip/hip_fp16.h>
#include <math.h>

#define PATCH 41
#define PSIZE (PATCH * PATCH)   // 1681
#define NUM_ANG 8
#define KS 16
#define STRIDE 10
#define PAD 4
#define DESC 128
#define CLIPVAL 0.2f

#define PROW 42                  // plane row stride in halves = 21 dwords (ODD)
#define PLANE_H 1722             // plane stride in halves = 861 dwords (ODD)
#define NQ4 (PATCH * 10)         // 410 uniform quads (x = 0..39)
#define CST 36                   // colsum row stride (floats)
#define NROWPAIR 21              // half2 pairs per row

struct F4 { float x, y, z, w; };

#if __has_builtin(__builtin_amdgcn_fdot2)
#define HAVE_FDOT2 1
typedef _Float16 h2v __attribute__((ext_vector_type(2)));
#endif

// Block-wide sum over 512 threads (threads with no value pass 0).
__device__ __forceinline__ float block_sum512(float v, float* red, int tid) {
    #pragma unroll
    for (int off = 32; off >= 1; off >>= 1) v += __shfl_xor(v, off);
    __syncthreads();                 // protect red[] from previous use
    if ((tid & 63) == 0) red[tid >> 6] = v;
    __syncthreads();
    float s = red[0];
    #pragma unroll
    for (int w = 1; w < 8; ++w) s += red[w];
    return s;
}

// per-pixel: gradient -> orientation -> two b16 plane writes
__device__ __forceinline__ void bin_px(__half* harr, int yx, float gx, float gy, float gkv) {
    float g2 = fmaf(gx, gx, 1e-10f);
    g2 = fmaf(gy, gy, g2);
    const float mag = __builtin_amdgcn_sqrtf(g2) * (gkv * 1024.0f);

    const float gxp = gx + 1e-10f;
    const float ax = fabsf(gxp), ay = fabsf(gy);
    const float mx = fmaxf(ax, ay);
    const float mn = fminf(ax, ay);
    const float t  = mn * __builtin_amdgcn_rcpf(fmaxf(mx, 1e-20f));
    const float s  = t * t;
    float r = t * fmaf(s, fmaf(s, fmaf(s, fmaf(s, 0.02652810f, -0.10839420f),
                                       0.22936229f), -0.42055650f), 1.27306897f);
    r = (ay > ax)    ? 2.0f - r : r;
    r = (gxp < 0.0f) ? 4.0f - r : r;
    r = (gy < 0.0f)  ? 8.0f - r : r;      // octant units in [0, 8]

    const float bf = floorf(r);
    const float f  = r - bf;
    const int b0 = ((int)bf) & (NUM_ANG - 1);
    const int b1 = (b0 + 1) & (NUM_ANG - 1);
    harr[b0 * PLANE_H + yx] = __float2half((1.0f - f) * mag);
    harr[b1 * PLANE_H + yx] = __float2half(f * mag);
}

__global__ __launch_bounds__(512) void sift_desc_kernel(
    const float* __restrict__ input,
    const float* __restrict__ gk,
    float* __restrict__ out)
{
    __shared__ __align__(16) __half s_arr[NUM_ANG * PLANE_H];  // 27552 B
    __shared__ float s_cs[PATCH * CST];                        // 5904 B
    __shared__ float s_red[8];

    const int tid = threadIdx.x;
    const int b   = blockIdx.x;
    const float* in_p = input + (size_t)b * PSIZE;
    __half* harr = s_arr;

    const float w1r[KS] = {0.0625f, 0.1875f, 0.3125f, 0.4375f,
                           0.5625f, 0.6875f, 0.8125f, 0.9375f,
                           0.9375f, 0.8125f, 0.6875f, 0.5625f,
                           0.4375f, 0.3125f, 0.1875f, 0.0625f};

    // ---- phase 0: zero the planes ----
    {
        float4* z = (float4*)s_arr;             // 1722 x 16B
        const float4 zero = make_float4(0.f, 0.f, 0.f, 0.f);
        for (int i = tid; i < NUM_ANG * PLANE_H / 8; i += 512) z[i] = zero;
    }
    __syncthreads();

    // ---- phase 1 (flat): one quad per thread; tail column on idle wave-7 threads ----
    if (tid < NQ4) {
        const int y  = tid / 10;
        const int xq = (tid - y * 10) * 4;
        const int ym = max(y - 1, 0), yp = min(y + 1, PATCH - 1);
        const float* cr = in_p + y  * PATCH;
        const float* ur = in_p + ym * PATCH;
        const float* dr = in_p + yp * PATCH;
        const float* gr = gk + y * PATCH;
        const int yx = y * PROW + xq;

        const F4 c = *(const F4*)(cr + xq);
        const F4 u = *(const F4*)(ur + xq);
        const F4 d = *(const F4*)(dr + xq);
        const F4 g = *(const F4*)(gr + xq);
        const float L = cr[max(xq - 1, 0)];
        const float R = cr[xq + 4];

        bin_px(harr, yx,     0.5f*(c.y - L),   0.5f*(d.x - u.x), g.x);
        bin_px(harr, yx + 1, 0.5f*(c.z - c.x), 0.5f*(d.y - u.y), g.y);
        bin_px(harr, yx + 2, 0.5f*(c.w - c.y), 0.5f*(d.z - u.z), g.z);
        bin_px(harr, yx + 3, 0.5f*(R  - c.z),  0.5f*(d.w - u.w), g.w);
    } else if (tid >= 448 && tid < 448 + PATCH) {   // tail column x = 40, concurrent
        const int y = tid - 448;
        const int ym = max(y - 1, 0), yp = min(y + 1, PATCH - 1);
        const float* cr = in_p + y * PATCH;
        bin_px(harr, y * PROW + 40,
               0.5f*(cr[40] - cr[39]),
               0.5f*(in_p[yp * PATCH + 40] - in_p[ym * PATCH + 40]),
               gk[y * PATCH + 40]);
    }
    __syncthreads();

    // ---- phase 2a (flat): one item per thread (tid < 328); row read ONCE as 21 b32 ----
    if (tid < NUM_ANG * PATCH) {
        const int a = tid & 7;
        const int y = tid >> 3;

        __half2 row[NROWPAIR];
        const __half2* rp = (const __half2*)(harr + a * PLANE_H + y * PROW);
        #pragma unroll
        for (int i = 0; i < NROWPAIR; ++i) row[i] = rp[i];

        float acc0 = 0.f, acc1 = 0.f, acc2 = 0.f, acc3 = 0.f;
#ifdef HAVE_FDOT2
        #define DOT(ACC, P, W0, W1) \
            ACC = __builtin_amdgcn_fdot2(*(const h2v*)&row[P], \
                    (h2v){(_Float16)(W0), (_Float16)(W1)}, ACC, false)
#else
        #define DOT(ACC, P, W0, W1) \
            ACC = fmaf((W0), __half2float(row[P].x), \
                  fmaf((W1), __half2float(row[P].y), ACC))
#endif
        // j=0: px 0..11 -> pairs 0..5, weights w1r[4..15]
        DOT(acc0, 0, 0.5625f, 0.6875f); DOT(acc0, 1, 0.8125f, 0.9375f);
        DOT(acc0, 2, 0.9375f, 0.8125f); DOT(acc0, 3, 0.6875f, 0.5625f);
        DOT(acc0, 4, 0.4375f, 0.3125f); DOT(acc0, 5, 0.1875f, 0.0625f);
        // j=1: px 6..21 -> pairs 3..10
        DOT(acc1, 3, 0.0625f, 0.1875f); DOT(acc1, 4, 0.3125f, 0.4375f);
        DOT(acc1, 5, 0.5625f, 0.6875f); DOT(acc1, 6, 0.8125f, 0.9375f);
        DOT(acc1, 7, 0.9375f, 0.8125f); DOT(acc1, 8, 0.6875f, 0.5625f);
        DOT(acc1, 9, 0.4375f, 0.3125f); DOT(acc1, 10, 0.1875f, 0.0625f);
        // j=2: px 16..31 -> pairs 8..15
        DOT(acc2, 8, 0.0625f, 0.1875f); DOT(acc2, 9, 0.3125f, 0.4375f);
        DOT(acc2, 10, 0.5625f, 0.6875f); DOT(acc2, 11, 0.8125f, 0.9375f);
        DOT(acc2, 12, 0.9375f, 0.8125f); DOT(acc2, 13, 0.6875f, 0.5625f);
        DOT(acc2, 14, 0.4375f, 0.3125f); DOT(acc2, 15, 0.1875f, 0.0625f);
        // j=3: px 26..41 -> pairs 13..20 (half 41 is zero pad)
        DOT(acc3, 13, 0.0625f, 0.1875f); DOT(acc3, 14, 0.3125f, 0.4375f);
        DOT(acc3, 15, 0.5625f, 0.6875f); DOT(acc3, 16, 0.8125f, 0.9375f);
        DOT(acc3, 17, 0.9375f, 0.8125f); DOT(acc3, 18, 0.6875f, 0.5625f);
        DOT(acc3, 19, 0.4375f, 0.3125f); DOT(acc3, 20, 0.1875f, 0.0625f);
        #undef DOT

        float* cs = s_cs + y * CST + a;
        cs[0]  = acc0;
        cs[8]  = acc1;
        cs[16] = acc2;
        cs[24] = acc3;
    }
    __syncthreads();

    // ---- phase 2b: y-pooling -> one descriptor value per tid < 128 ----
    float v = 0.0f;
    int a = 0, jj = 0, ii = 0;
    if (tid < DESC) {
        a = tid & 7; jj = (tid >> 3) & 3; ii = tid >> 5;
        const int py0 = ii * STRIDE - PAD;
        #pragma unroll
        for (int dy = 0; dy < KS; ++dy) {
            const int py  = py0 + dy;
            const int pyc = min(max(py, 0), PATCH - 1);
            const float wv = (py == pyc) ? w1r[dy] : 0.0f;
            v = fmaf(wv, s_cs[pyc * CST + jj * 8 + a], v);
        }
    }

    // ---- normalization chain: l2n -> clip -> l2n -> rootsift ----
    const float ss1 = block_sum512(v * v, s_red, tid);
    float aa = v / fmaxf(sqrtf(ss1), 1e-12f);
    aa = fminf(fmaxf(aa, 0.0f), CLIPVAL);

    const float ss2 = block_sum512(aa * aa, s_red, tid);
    const float bn = aa / fmaxf(sqrtf(ss2), 1e-12f);

    const float l1 = block_sum512(fabsf(bn), s_red, tid);
    const float o  = sqrtf(bn / fmaxf(l1, 1e-12f) + 1e-10f);

    // reference layout: desc[ang*16 + i*4 + j]
    if (tid < DESC) out[(size_t)b * DESC + (a * 16 + ii * 4 + jj)] = o;
}

extern "C" void kernel_launch(void* const* d_in, const int* in_sizes, int n_in,
                              void* d_out, int out_size, void* d_ws, size_t ws_size,
                              hipStream_t stream) {
    const float* input = (const float*)d_in[0];
    const float* gk    = (const float*)d_in[1];
    float* out         = (float*)d_out;

    const int B = in_sizes[0] / PSIZE;
    if (B <= 0) return;
    sift_desc_kernel<<<dim3(B), dim3(512), 0, stream>>>(input, gk, out);
}

// Round 15
// 36.391 us; speedup vs baseline: 3.1582x; 1.3120x over previous
//
#include <hip/hip_runtime.h>
#include <hip/hip_fp16.h>
#include <math.h>

#define PATCH 41
#define PSIZE (PATCH * PATCH)   // 1681
#define NUM_ANG 8
#define KS 16
#define STRIDE 10
#define PAD 4
#define DESC 128
#define CLIPVAL 0.2f

#define PROW 42                  // plane row stride in halves = 21 dwords (ODD)
#define PLANE_H 1722             // plane stride in halves = 861 dwords (ODD)
#define NQ4 (PATCH * 10)         // 410 uniform quads (x = 0..39)
#define CST 36                   // colsum row stride (floats)
#define NROWPAIR 21              // half2 pairs per row

struct F4 { float x, y, z, w; };

#if __has_builtin(__builtin_amdgcn_fdot2)
#define HAVE_FDOT2 1
typedef _Float16 h2v __attribute__((ext_vector_type(2)));
#endif

// ---- DPP-based wave64 sum (VALU pipe only, no LDS, no barriers) ----
template <int CTRL>
__device__ __forceinline__ float dpp_add(float v) {
    const int s = __builtin_amdgcn_update_dpp(
        0, __builtin_bit_cast(int, v), CTRL, 0xF, 0xF, true);
    return v + __builtin_bit_cast(float, s);
}
__device__ __forceinline__ float wave_sum_dpp(float v) {
    v = dpp_add<0x111>(v);   // row_shr:1
    v = dpp_add<0x112>(v);   // row_shr:2
    v = dpp_add<0x114>(v);   // row_shr:4
    v = dpp_add<0x118>(v);   // row_shr:8  -> lane 15 of each row = row sum
    v = dpp_add<0x142>(v);   // row_bcast:15
    v = dpp_add<0x143>(v);   // row_bcast:31 -> lane 63 = total
    return __builtin_bit_cast(float,
        __builtin_amdgcn_readlane(__builtin_bit_cast(int, v), 63));
}

// per-pixel: gradient -> orientation -> two b16 plane writes
__device__ __forceinline__ void bin_px(__half* harr, int yx, float gx, float gy, float gkv) {
    float g2 = fmaf(gx, gx, 1e-10f);
    g2 = fmaf(gy, gy, g2);
    const float mag = __builtin_amdgcn_sqrtf(g2) * (gkv * 1024.0f);

    const float gxp = gx + 1e-10f;
    const float ax = fabsf(gxp), ay = fabsf(gy);
    const float mx = fmaxf(ax, ay);
    const float mn = fminf(ax, ay);
    const float t  = mn * __builtin_amdgcn_rcpf(fmaxf(mx, 1e-20f));
    const float s  = t * t;
    float r = t * fmaf(s, fmaf(s, fmaf(s, fmaf(s, 0.02652810f, -0.10839420f),
                                       0.22936229f), -0.42055650f), 1.27306897f);
    r = (ay > ax)    ? 2.0f - r : r;
    r = (gxp < 0.0f) ? 4.0f - r : r;
    r = (gy < 0.0f)  ? 8.0f - r : r;      // octant units in [0, 8]

    const float bf = floorf(r);
    const float f  = r - bf;
    const int b0 = ((int)bf) & (NUM_ANG - 1);
    const int b1 = (b0 + 1) & (NUM_ANG - 1);
    harr[b0 * PLANE_H + yx] = __float2half((1.0f - f) * mag);
    harr[b1 * PLANE_H + yx] = __float2half(f * mag);
}

__global__ __launch_bounds__(512) void sift_desc_kernel(
    const float* __restrict__ input,
    const float* __restrict__ gk,
    float* __restrict__ out)
{
    __shared__ __align__(16) __half s_arr[NUM_ANG * PLANE_H];  // 27552 B
    __shared__ float s_cs[PATCH * CST];                        // 5904 B

    const int tid = threadIdx.x;
    const int b   = blockIdx.x;
    const float* in_p = input + (size_t)b * PSIZE;
    __half* harr = s_arr;

    const float w1r[KS] = {0.0625f, 0.1875f, 0.3125f, 0.4375f,
                           0.5625f, 0.6875f, 0.8125f, 0.9375f,
                           0.9375f, 0.8125f, 0.6875f, 0.5625f,
                           0.4375f, 0.3125f, 0.1875f, 0.0625f};

    // ---- phase 0: zero the planes ----
    {
        float4* z = (float4*)s_arr;             // 1722 x 16B
        const float4 zero = make_float4(0.f, 0.f, 0.f, 0.f);
        for (int i = tid; i < NUM_ANG * PLANE_H / 8; i += 512) z[i] = zero;
    }
    __syncthreads();

    // ---- phase 1 (flat): one quad per thread; tail column on idle wave-7 threads ----
    if (tid < NQ4) {
        const int y  = tid / 10;
        const int xq = (tid - y * 10) * 4;
        const int ym = max(y - 1, 0), yp = min(y + 1, PATCH - 1);
        const float* cr = in_p + y  * PATCH;
        const float* ur = in_p + ym * PATCH;
        const float* dr = in_p + yp * PATCH;
        const float* gr = gk + y * PATCH;
        const int yx = y * PROW + xq;

        const F4 c = *(const F4*)(cr + xq);
        const F4 u = *(const F4*)(ur + xq);
        const F4 d = *(const F4*)(dr + xq);
        const F4 g = *(const F4*)(gr + xq);
        const float L = cr[max(xq - 1, 0)];
        const float R = cr[xq + 4];

        bin_px(harr, yx,     0.5f*(c.y - L),   0.5f*(d.x - u.x), g.x);
        bin_px(harr, yx + 1, 0.5f*(c.z - c.x), 0.5f*(d.y - u.y), g.y);
        bin_px(harr, yx + 2, 0.5f*(c.w - c.y), 0.5f*(d.z - u.z), g.z);
        bin_px(harr, yx + 3, 0.5f*(R  - c.z),  0.5f*(d.w - u.w), g.w);
    } else if (tid >= 448 && tid < 448 + PATCH) {   // tail column x = 40, concurrent
        const int y = tid - 448;
        const int ym = max(y - 1, 0), yp = min(y + 1, PATCH - 1);
        const float* cr = in_p + y * PATCH;
        bin_px(harr, y * PROW + 40,
               0.5f*(cr[40] - cr[39]),
               0.5f*(in_p[yp * PATCH + 40] - in_p[ym * PATCH + 40]),
               gk[y * PATCH + 40]);
    }
    __syncthreads();

    // ---- phase 2a (flat): one item per thread (tid < 328); row read ONCE ----
    if (tid < NUM_ANG * PATCH) {
        const int a = tid & 7;
        const int y = tid >> 3;

        __half2 row[NROWPAIR];
        const __half2* rp = (const __half2*)(harr + a * PLANE_H + y * PROW);
        #pragma unroll
        for (int i = 0; i < NROWPAIR; ++i) row[i] = rp[i];

        float acc0 = 0.f, acc1 = 0.f, acc2 = 0.f, acc3 = 0.f;
#ifdef HAVE_FDOT2
        #define DOT(ACC, P, W0, W1) \
            ACC = __builtin_amdgcn_fdot2(*(const h2v*)&row[P], \
                    (h2v){(_Float16)(W0), (_Float16)(W1)}, ACC, false)
#else
        #define DOT(ACC, P, W0, W1) \
            ACC = fmaf((W0), __half2float(row[P].x), \
                  fmaf((W1), __half2float(row[P].y), ACC))
#endif
        // j=0: px 0..11 -> pairs 0..5, weights w1r[4..15]
        DOT(acc0, 0, 0.5625f, 0.6875f); DOT(acc0, 1, 0.8125f, 0.9375f);
        DOT(acc0, 2, 0.9375f, 0.8125f); DOT(acc0, 3, 0.6875f, 0.5625f);
        DOT(acc0, 4, 0.4375f, 0.3125f); DOT(acc0, 5, 0.1875f, 0.0625f);
        // j=1: px 6..21 -> pairs 3..10
        DOT(acc1, 3, 0.0625f, 0.1875f); DOT(acc1, 4, 0.3125f, 0.4375f);
        DOT(acc1, 5, 0.5625f, 0.6875f); DOT(acc1, 6, 0.8125f, 0.9375f);
        DOT(acc1, 7, 0.9375f, 0.8125f); DOT(acc1, 8, 0.6875f, 0.5625f);
        DOT(acc1, 9, 0.4375f, 0.3125f); DOT(acc1, 10, 0.1875f, 0.0625f);
        // j=2: px 16..31 -> pairs 8..15
        DOT(acc2, 8, 0.0625f, 0.1875f); DOT(acc2, 9, 0.3125f, 0.4375f);
        DOT(acc2, 10, 0.5625f, 0.6875f); DOT(acc2, 11, 0.8125f, 0.9375f);
        DOT(acc2, 12, 0.9375f, 0.8125f); DOT(acc2, 13, 0.6875f, 0.5625f);
        DOT(acc2, 14, 0.4375f, 0.3125f); DOT(acc2, 15, 0.1875f, 0.0625f);
        // j=3: px 26..41 -> pairs 13..20 (half 41 is zero pad)
        DOT(acc3, 13, 0.0625f, 0.1875f); DOT(acc3, 14, 0.3125f, 0.4375f);
        DOT(acc3, 15, 0.5625f, 0.6875f); DOT(acc3, 16, 0.8125f, 0.9375f);
        DOT(acc3, 17, 0.9375f, 0.8125f); DOT(acc3, 18, 0.6875f, 0.5625f);
        DOT(acc3, 19, 0.4375f, 0.3125f); DOT(acc3, 20, 0.1875f, 0.0625f);
        #undef DOT

        float* cs = s_cs + y * CST + a;
        cs[0]  = acc0;
        cs[8]  = acc1;
        cs[16] = acc2;
        cs[24] = acc3;
    }
    __syncthreads();

    // ---- phases 2b + norm: single wave, DPP reductions (no LDS shuffles) ----
    if (tid < 64) {
        const int lane = tid;
        float v0 = 0.0f, v1 = 0.0f;
        int a0i = 0, jj0 = 0, ii0 = 0, a1i = 0, jj1 = 0, ii1 = 0;
        #pragma unroll
        for (int h = 0; h < 2; ++h) {
            const int item = lane + h * 64;
            const int a  = item & 7;
            const int jj = (item >> 3) & 3;
            const int ii = item >> 5;
            const int py0 = ii * STRIDE - PAD;
            float s = 0.0f;
            #pragma unroll
            for (int dy = 0; dy < KS; ++dy) {
                const int py  = py0 + dy;
                const int pyc = min(max(py, 0), PATCH - 1);
                const float wv = (py == pyc) ? w1r[dy] : 0.0f;
                s = fmaf(wv, s_cs[pyc * CST + jj * 8 + a], s);
            }
            if (h == 0) { v0 = s; a0i = a; jj0 = jj; ii0 = ii; }
            else        { v1 = s; a1i = a; jj1 = jj; ii1 = ii; }
        }

        // l2n -> clip -> l2n -> rootsift, reductions on the VALU pipe
        const float ss1 = wave_sum_dpp(fmaf(v0, v0, v1 * v1));
        const float inv1 = 1.0f / fmaxf(sqrtf(ss1), 1e-12f);
        const float c0 = fminf(fmaxf(v0 * inv1, 0.0f), CLIPVAL);
        const float c1 = fminf(fmaxf(v1 * inv1, 0.0f), CLIPVAL);

        const float ss2 = wave_sum_dpp(fmaf(c0, c0, c1 * c1));
        const float inv2 = 1.0f / fmaxf(sqrtf(ss2), 1e-12f);
        const float b0 = c0 * inv2;
        const float b1 = c1 * inv2;

        const float l1 = wave_sum_dpp(fabsf(b0) + fabsf(b1));
        const float invl = 1.0f / fmaxf(l1, 1e-12f);
        const float o0 = sqrtf(fmaf(b0, invl, 1e-10f));
        const float o1 = sqrtf(fmaf(b1, invl, 1e-10f));

        // reference layout: desc[ang*16 + i*4 + j]
        out[(size_t)b * DESC + (a0i * 16 + ii0 * 4 + jj0)] = o0;
        out[(size_t)b * DESC + (a1i * 16 + ii1 * 4 + jj1)] = o1;
    }
}

extern "C" void kernel_launch(void* const* d_in, const int* in_sizes, int n_in,
                              void* d_out, int out_size, void* d_ws, size_t ws_size,
                              hipStream_t stream) {
    const float* input = (const float*)d_in[0];
    const float* gk    = (const float*)d_in[1];
    float* out         = (float*)d_out;

    const int B = in_sizes[0] / PSIZE;
    if (B <= 0) return;
    sift_desc_kernel<<<dim3(B), dim3(512), 0, stream>>>(input, gk, out);
}

// Round 16
// 35.999 us; speedup vs baseline: 3.1926x; 1.0109x over previous
//
#include <hip/hip_runtime.h>
#include <hip/hip_fp16.h>
#include <math.h>

#define PATCH 41
#define PSIZE (PATCH * PATCH)   // 1681
#define NUM_ANG 8
#define KS 16
#define STRIDE 10
#define PAD 4
#define DESC 128
#define CLIPVAL 0.2f

#define NQ4 (PATCH * 10)         // 410 uniform quads (x = 0..39)
#define CST 33                   // colsum row stride (floats, ODD -> bank spread)
#define ROWH (PATCH * 8)         // s_bins row stride in halves

struct F4 { float x, y, z, w; };

// ---- DPP-based wave64 sum (VALU pipe only, no LDS, no barriers) ----
template <int CTRL>
__device__ __forceinline__ float dpp_add(float v) {
    const int s = __builtin_amdgcn_update_dpp(
        0, __builtin_bit_cast(int, v), CTRL, 0xF, 0xF, true);
    return v + __builtin_bit_cast(float, s);
}
__device__ __forceinline__ float wave_sum_dpp(float v) {
    v = dpp_add<0x111>(v);   // row_shr:1
    v = dpp_add<0x112>(v);   // row_shr:2
    v = dpp_add<0x114>(v);   // row_shr:4
    v = dpp_add<0x118>(v);   // row_shr:8
    v = dpp_add<0x142>(v);   // row_bcast:15
    v = dpp_add<0x143>(v);   // row_bcast:31 -> lane 63 = total
    return __builtin_bit_cast(float,
        __builtin_amdgcn_readlane(__builtin_bit_cast(int, v), 63));
}

// per-pixel: UN-HALVED gradients -> orientation -> two b16 slot writes
// (0.5 scale folded into gkv*512; eps folded consistently: 4e-10 / 2e-10)
__device__ __forceinline__ void bin_px(__half* sb, int pix, float gx2, float gy2, float gkv) {
    float g2 = fmaf(gx2, gx2, 4e-10f);
    g2 = fmaf(gy2, gy2, g2);
    const float mag = __builtin_amdgcn_sqrtf(g2) * (gkv * 512.0f);

    const float gxp = gx2 + 2e-10f;
    const float ax = fabsf(gxp), ay = fabsf(gy2);
    const float mx = fmaxf(ax, ay);
    const float mn = fminf(ax, ay);
    const float t  = mn * __builtin_amdgcn_rcpf(fmaxf(mx, 1e-20f));
    const float s  = t * t;
    float r = t * fmaf(s, fmaf(s, fmaf(s, fmaf(s, 0.02652810f, -0.10839420f),
                                       0.22936229f), -0.42055650f), 1.27306897f);
    r = (ay > ax)     ? 2.0f - r : r;
    r = (gxp < 0.0f)  ? 4.0f - r : r;
    r = (gy2 < 0.0f)  ? 8.0f - r : r;      // octant units in [0, 8]

    const float bf = floorf(r);
    const float f  = r - bf;
    const int b0 = ((int)bf) & (NUM_ANG - 1);
    const int b1 = (b0 + 1) & (NUM_ANG - 1);
    __half* slot = sb + pix * NUM_ANG;
    slot[b0] = __float2half((1.0f - f) * mag);
    slot[b1] = __float2half(f * mag);
}

__global__ __launch_bounds__(512) void sift_desc_kernel(
    const float* __restrict__ input,
    const float* __restrict__ gk,
    float* __restrict__ out)
{
    __shared__ __align__(16) __half s_bins[PSIZE * NUM_ANG];  // 26896 B, [pix][a]
    __shared__ float s_cs[PATCH * CST];                       // 5412 B

    const int tid = threadIdx.x;
    const int b   = blockIdx.x;
    const float* in_p = input + (size_t)b * PSIZE;

    const float w1r[KS] = {0.0625f, 0.1875f, 0.3125f, 0.4375f,
                           0.5625f, 0.6875f, 0.8125f, 0.9375f,
                           0.9375f, 0.8125f, 0.6875f, 0.5625f,
                           0.4375f, 0.3125f, 0.1875f, 0.0625f};

    // ---- phase 0: zero the bins (1681 x 16B) ----
    {
        float4* z = (float4*)s_bins;
        const float4 zero = make_float4(0.f, 0.f, 0.f, 0.f);
        for (int i = tid; i < PSIZE; i += 512) z[i] = zero;
    }
    __syncthreads();

    // ---- phase 1 (flat): one quad/thread; tail column on wave-7 threads ----
    if (tid < NQ4) {
        const int y  = tid / 10;
        const int xq = (tid - y * 10) * 4;
        const int ym = max(y - 1, 0), yp = min(y + 1, PATCH - 1);
        const float* cr = in_p + y  * PATCH;
        const float* ur = in_p + ym * PATCH;
        const float* dr = in_p + yp * PATCH;
        const float* gr = gk + y * PATCH;
        const int pix = y * PATCH + xq;

        const F4 c = *(const F4*)(cr + xq);
        const F4 u = *(const F4*)(ur + xq);
        const F4 d = *(const F4*)(dr + xq);
        const F4 g = *(const F4*)(gr + xq);
        const float L = cr[max(xq - 1, 0)];
        const float R = cr[xq + 4];

        bin_px(s_bins, pix,     (c.y - L),   (d.x - u.x), g.x);
        bin_px(s_bins, pix + 1, (c.z - c.x), (d.y - u.y), g.y);
        bin_px(s_bins, pix + 2, (c.w - c.y), (d.z - u.z), g.z);
        bin_px(s_bins, pix + 3, (R  - c.z),  (d.w - u.w), g.w);
    } else if (tid >= 448 && tid < 448 + PATCH) {   // tail column x = 40
        const int y = tid - 448;
        const int ym = max(y - 1, 0), yp = min(y + 1, PATCH - 1);
        const float* cr = in_p + y * PATCH;
        bin_px(s_bins, y * PATCH + 40,
               (cr[40] - cr[39]),
               (in_p[yp * PATCH + 40] - in_p[ym * PATCH + 40]),
               gk[y * PATCH + 40]);
    }
    __syncthreads();

    // ---- phase 2a: thread = (angle-pair k, row y); 41 stride-16B b32 reads ----
    if (tid < PATCH * 4) {
        const int k = tid & 3;        // angle pair: angles 2k, 2k+1
        const int y = tid >> 2;
        const __half* sb = s_bins + y * ROWH + k * 2;

        float acc[8];                 // [j][0/1]
        #pragma unroll
        for (int i = 0; i < 8; ++i) acc[i] = 0.0f;

        #pragma unroll
        for (int x = 0; x < PATCH; ++x) {
            const __half2 h = *(const __half2*)(sb + x * NUM_ANG);
            const float h0 = __half2float(h.x);
            const float h1 = __half2float(h.y);
            #pragma unroll
            for (int j = 0; j < 4; ++j) {
                const int dd = x - (j * STRIDE - PAD);
                if (dd >= 0 && dd < KS) {           // compile-time after unroll
                    const float w = ((dd < 8 ? dd : 15 - dd) + 0.5f) * 0.125f;
                    acc[j * 2]     = fmaf(w, h0, acc[j * 2]);
                    acc[j * 2 + 1] = fmaf(w, h1, acc[j * 2 + 1]);
                }
            }
        }
        float* cs = s_cs + y * CST + k * 2;
        #pragma unroll
        for (int j = 0; j < 4; ++j) {
            cs[j * 8]     = acc[j * 2];
            cs[j * 8 + 1] = acc[j * 2 + 1];
        }
    }
    __syncthreads();

    // ---- phases 2b + norm: single wave, DPP reductions ----
    if (tid < 64) {
        const int lane = tid;
        float v0 = 0.0f, v1 = 0.0f;
        int a0i = 0, jj0 = 0, ii0 = 0, a1i = 0, jj1 = 0, ii1 = 0;
        #pragma unroll
        for (int h = 0; h < 2; ++h) {
            const int item = lane + h * 64;
            const int a  = item & 7;
            const int jj = (item >> 3) & 3;
            const int ii = item >> 5;
            const int py0 = ii * STRIDE - PAD;
            float s = 0.0f;
            #pragma unroll
            for (int dy = 0; dy < KS; ++dy) {
                const int py  = py0 + dy;
                const int pyc = min(max(py, 0), PATCH - 1);
                const float wv = (py == pyc) ? w1r[dy] : 0.0f;
                s = fmaf(wv, s_cs[pyc * CST + jj * 8 + a], s);
            }
            if (h == 0) { v0 = s; a0i = a; jj0 = jj; ii0 = ii; }
            else        { v1 = s; a1i = a; jj1 = jj; ii1 = ii; }
        }

        const float ss1 = wave_sum_dpp(fmaf(v0, v0, v1 * v1));
        const float inv1 = 1.0f / fmaxf(sqrtf(ss1), 1e-12f);
        const float c0 = fminf(fmaxf(v0 * inv1, 0.0f), CLIPVAL);
        const float c1 = fminf(fmaxf(v1 * inv1, 0.0f), CLIPVAL);

        const float ss2 = wave_sum_dpp(fmaf(c0, c0, c1 * c1));
        const float inv2 = 1.0f / fmaxf(sqrtf(ss2), 1e-12f);
        const float b0 = c0 * inv2;
        const float b1 = c1 * inv2;

        const float l1 = wave_sum_dpp(fabsf(b0) + fabsf(b1));
        const float invl = 1.0f / fmaxf(l1, 1e-12f);
        const float o0 = sqrtf(fmaf(b0, invl, 1e-10f));
        const float o1 = sqrtf(fmaf(b1, invl, 1e-10f));

        // reference layout: desc[ang*16 + i*4 + j]
        out[(size_t)b * DESC + (a0i * 16 + ii0 * 4 + jj0)] = o0;
        out[(size_t)b * DESC + (a1i * 16 + ii1 * 4 + jj1)] = o1;
    }
}

extern "C" void kernel_launch(void* const* d_in, const int* in_sizes, int n_in,
                              void* d_out, int out_size, void* d_ws, size_t ws_size,
                              hipStream_t stream) {
    const float* input = (const float*)d_in[0];
    const float* gk    = (const float*)d_in[1];
    float* out         = (float*)d_out;

    const int B = in_sizes[0] / PSIZE;
    if (B <= 0) return;
    sift_desc_kernel<<<dim3(B), dim3(512), 0, stream>>>(input, gk, out);
}